// Round 19
// baseline (162.261 us; speedup 1.0000x reference)
//
#include <hip/hip_runtime.h>
#include <hip/hip_fp8.h>

// VGCN layer (R19 = R18 with operand-SWAPPED GEMM):
//   A1/A2/B: two-level scatter-free CSR build (unchanged, proven)
//   C : wave-per-node gather, wave-uniform masked 8-deep fp8 pipeline (proven)
//   D : bf16 MFMA GEMM computing D = W_tile x agg^T: D col = node, row = j,
//       so each lane's f32x4 = 4 CONSECUTIVE features of ONE node ->
//       float4 epilogue with no LDS/shuffles (R18 showed gemm is
//       memory-instruction-issue-bound: 192 scalar ops/thread ~= 31us floor)

#define DIM 128
#define BN 128            // nodes per fine bucket
#define MAXNB 1024        // max fine buckets
#define CAP 3072          // fine-bucket capacity (mean ~2048, sigma ~45)
#define L1BITS 13         // L1 bucket = 8192 nodes
#define MAXL1 16
#define CAP1 147456       // L1 capacity (mean 131072, sigma ~347) = 72*2048
#define NCHK 72           // part2 chunks per L1 bucket (NCHK*2048 == CAP1)
#define C1 8              // edges/thread, phase A1
#define C2 8              // edges/thread, phase A2

typedef __attribute__((ext_vector_type(8))) short short8v;   // 8 bf16
typedef __attribute__((ext_vector_type(4))) float f32x4;     // MFMA acc

static __device__ __forceinline__ unsigned short f2b(float f) {
    unsigned u = __float_as_uint(f);
    unsigned r = (u >> 16) & 1;          // round-to-nearest-even
    u += 0x7fffu + r;
    return (unsigned short)(u >> 16);
}

static __device__ __forceinline__ unsigned char f2fp8(float f) {
    __hip_fp8_e4m3 h(f);                 // OCP e4m3fn, HW convert on gfx950
    return h.__x;
}
static __device__ __forceinline__ float fp82f(unsigned char b) {
    __hip_fp8_e4m3 h; h.__x = b;
    return (float)h;
}

// A1: 13-bin partition, coalesced appends of packed (dst&8191)<<17|src
__global__ __launch_bounds__(256) void part1_k(const int* __restrict__ src,
                                               const int* __restrict__ dst,
                                               int* __restrict__ gcur1,
                                               int* __restrict__ l1,
                                               int E, int NL1) {
    __shared__ int stage[256 * C1];
    __shared__ int hist[MAXL1], excl[MAXL1], gbase[MAXL1];
    int tid = threadIdx.x, lane = tid & 63, wid = tid >> 6;
    int e0 = blockIdx.x * 256 * C1;
    int bk[C1], pk[C1];
    #pragma unroll
    for (int k = 0; k < C1; k++) {
        int e = e0 + k * 256 + tid;
        bool valid = e < E;
        int d = valid ? __builtin_nontemporal_load(dst + e) : 0;
        int s = valid ? __builtin_nontemporal_load(src + e) : 0;
        bk[k] = valid ? (d >> L1BITS) : -1;
        pk[k] = ((d & 8191) << 17) | s;
    }
    if (tid < MAXL1) hist[tid] = 0;
    __syncthreads();
    #pragma unroll
    for (int k = 0; k < C1; k++)
        if (bk[k] >= 0) atomicAdd(&hist[bk[k]], 1);
    __syncthreads();
    if (tid == 0) { int run = 0; for (int b = 0; b < NL1; b++) { excl[b] = run; run += hist[b]; } }
    __syncthreads();
    if (tid < MAXL1) hist[tid] = 0;              // reuse as cursor
    __syncthreads();
    #pragma unroll
    for (int k = 0; k < C1; k++)
        if (bk[k] >= 0) {
            int pos = excl[bk[k]] + atomicAdd(&hist[bk[k]], 1);
            stage[pos] = pk[k];
        }
    __syncthreads();
    if (tid < NL1) { int c = hist[tid]; gbase[tid] = c ? atomicAdd(&gcur1[tid], c) : 0; }
    __syncthreads();
    for (int b = wid; b < NL1; b += 4) {
        int c = hist[b], eo = excl[b], gb = gbase[b];
        int cw = c;                                   // partial flush on overflow
        if (gb >= CAP1) cw = 0;
        else if (gb + cw > CAP1) cw = CAP1 - gb;
        if (cw > 0) {
            int* dp = l1 + (size_t)b * CAP1 + gb;
            for (int i = lane; i < cw; i += 64)
                __builtin_nontemporal_store(stage[eo + i], dp + i);
        }
    }
}

// A2: split each L1 list into NCHK chunks of 2048; 64-bin partition into fine
// buckets. fine-local id = (v>>24)&63; repack = v & 0xFFFFFF.
__global__ __launch_bounds__(256) void part2_k(const int* __restrict__ l1,
                                               const int* __restrict__ gcur1,
                                               int* __restrict__ gcur,
                                               int* __restrict__ pairs) {
    __shared__ int stage[256 * C2];
    __shared__ int hist[64], excl[64], gbase[64];
    int tid = threadIdx.x, lane = tid & 63, wid = tid >> 6;
    int b1 = blockIdx.x / NCHK, q = blockIdx.x % NCHK;
    int cnt = gcur1[b1];
    if (cnt < 0) cnt = 0;
    if (cnt > CAP1) cnt = CAP1;
    int start = q * 256 * C2;
    const int* pl = l1 + (size_t)b1 * CAP1;
    int bk[C2], pk[C2];
    #pragma unroll
    for (int k = 0; k < C2; k++) {
        int i = start + k * 256 + tid;
        bool valid = i < cnt;
        int v = valid ? __builtin_nontemporal_load(pl + i) : 0;
        bk[k] = valid ? ((v >> 24) & 63) : -1;
        pk[k] = v & 0xFFFFFF;
    }
    if (tid < 64) hist[tid] = 0;
    __syncthreads();
    #pragma unroll
    for (int k = 0; k < C2; k++)
        if (bk[k] >= 0) atomicAdd(&hist[bk[k]], 1);
    __syncthreads();
    if (wid == 0) {                               // wave-0 scan of 64 bins
        int v = hist[lane];
        int sc = v;
        #pragma unroll
        for (int o = 1; o < 64; o <<= 1) {
            int t = __shfl_up(sc, o);
            if (lane >= o) sc += t;
        }
        excl[lane] = sc - v;
    }
    __syncthreads();
    if (tid < 64) hist[tid] = 0;                  // reuse as cursor
    __syncthreads();
    #pragma unroll
    for (int k = 0; k < C2; k++)
        if (bk[k] >= 0) {
            int pos = excl[bk[k]] + atomicAdd(&hist[bk[k]], 1);
            stage[pos] = pk[k];
        }
    __syncthreads();
    if (tid < 64) {
        int c = hist[tid];
        gbase[tid] = c ? atomicAdd(&gcur[(b1 << 6) + tid], c) : 0;
    }
    __syncthreads();
    for (int b = wid; b < 64; b += 4) {
        int c = hist[b], eo = excl[b], gb = gbase[b];
        int cw = c;                                   // partial flush on overflow
        if (gb >= CAP) cw = 0;
        else if (gb + cw > CAP) cw = CAP - gb;
        if (cw > 0) {
            int* dp = pairs + (size_t)((b1 << 6) + b) * CAP + gb;
            for (int i = lane; i < cw; i += 64)
                __builtin_nontemporal_store(stage[eo + i], dp + i);
        }
    }
}

// exclusive scan of CLAMPED gcur (NB <= 1024) -> bbase; offsets[N] = total
__global__ __launch_bounds__(1024) void scan_gcur_k(const int* __restrict__ gcur,
                                                    int* __restrict__ bbase, int NB,
                                                    int* __restrict__ offsets, int N) {
    __shared__ int sh[1024];
    int t = threadIdx.x;
    int v = 0;
    if (t < NB) {
        v = gcur[t];
        if (v < 0) v = 0;
        if (v > CAP) v = CAP;
    }
    sh[t] = v;
    __syncthreads();
    for (int off = 1; off < 1024; off <<= 1) {
        int u = (t >= off) ? sh[t - off] : 0;
        __syncthreads();
        sh[t] += u;
        __syncthreads();
    }
    if (t < NB) bbase[t] = sh[t] - v;
    if (t == NB - 1) offsets[N] = sh[t];          // scanned total (== E normally)
}

// B: per-bucket counting sort in LDS; deg/offsets/sorted_src all coalesced.
__global__ __launch_bounds__(256) void bucket_csr_k(const int* __restrict__ pairs,
                                                    const int* __restrict__ gcur,
                                                    const int* __restrict__ bbase,
                                                    int* __restrict__ deg,
                                                    int* __restrict__ offsets,
                                                    int* __restrict__ sorted_src,
                                                    int N, int E) {
    __shared__ int pbuf[CAP];
    __shared__ int sbuf[CAP];
    __shared__ int hist[BN];
    __shared__ int excl[BN];
    __shared__ int cur[BN];
    int b = blockIdx.x, tid = threadIdx.x;
    int cnt = gcur[b];
    if (cnt < 0) cnt = 0;
    if (cnt > CAP) cnt = CAP;
    int base = bbase[b];
    if (base < 0) base = 0;
    if (base > E) base = E;
    if (base + cnt > E) cnt = E - base;          // never write past sorted_src[E]
    const int* pl = pairs + (size_t)b * CAP;
    for (int i = tid; i < cnt; i += 256) pbuf[i] = pl[i];
    if (tid < BN) { hist[tid] = 0; cur[tid] = 0; }
    __syncthreads();
    for (int i = tid; i < cnt; i += 256) atomicAdd(&hist[pbuf[i] >> 17], 1);
    __syncthreads();
    if (tid < BN) excl[tid] = hist[tid];
    __syncthreads();
    for (int off = 1; off < BN; off <<= 1) {         // Hillis-Steele inclusive
        int u = (tid < BN && tid >= off) ? excl[tid - off] : 0;
        __syncthreads();
        if (tid < BN) excl[tid] += u;
        __syncthreads();
    }
    if (tid < BN) excl[tid] -= hist[tid];            // -> exclusive
    __syncthreads();
    int nloc = N - b * BN; if (nloc > BN) nloc = BN;
    if (tid < nloc) {
        deg[b * BN + tid] = hist[tid];
        offsets[b * BN + tid] = base + excl[tid];
    }
    for (int i = tid; i < cnt; i += 256) {
        int v = pbuf[i];
        int pos = excl[v >> 17] + atomicAdd(&cur[v >> 17], 1);
        if (pos >= 0 && pos < CAP) sbuf[pos] = v & 0x1ffff;
    }
    __syncthreads();
    int* dp = sorted_src + base;
    for (int i = tid; i < cnt; i += 256) dp[i] = sbuf[i];
}

// W (fp32 row-major [j][k]) -> bf16
__global__ __launch_bounds__(256) void prep_w_k(const float* __restrict__ W,
                                                unsigned short* __restrict__ wb) {
    int i = blockIdx.x * 256 + threadIdx.x;
    if (i < DIM * DIM) wb[i] = f2b(W[i]);
}

// feat8[n][k] = fp8_e4m3(deg[n]^-1/2 * feat[n][k]); one thread per 4 elems
__global__ __launch_bounds__(256) void prescale_k(const float* __restrict__ feat,
                                                  const int* __restrict__ deg,
                                                  unsigned char* __restrict__ feat8,
                                                  int N) {
    int idx = blockIdx.x * 256 + threadIdx.x;
    int total = N * (DIM / 4);
    if (idx >= total) return;
    int n = idx >> 5;
    int dgi = deg[n];
    float dg = (float)(dgi < 1 ? 1 : dgi);
    float nrm = rsqrtf(dg);
    float4 f = ((const float4*)feat)[idx];
    unsigned v = (unsigned)f2fp8(f.x * nrm)
               | ((unsigned)f2fp8(f.y * nrm) << 8)
               | ((unsigned)f2fp8(f.z * nrm) << 16)
               | ((unsigned)f2fp8(f.w * nrm) << 24);
    ((unsigned*)feat8)[idx] = v;
}

// C: one wave per node; wave-uniform masked 8-deep gather over fp8 rows
// (128B/row, one coalesced row per load instruction). Proven R13 form.
__global__ __launch_bounds__(256) void aggregate_k(const unsigned char* __restrict__ feat8,
                                                   const int* __restrict__ offsets,
                                                   const int* __restrict__ sorted_src,
                                                   unsigned short* __restrict__ agg,
                                                   int N, int E) {
    int wave = (blockIdx.x * 256 + threadIdx.x) >> 6;
    int lane = threadIdx.x & 63;
    if (wave >= N) return;
    int s0 = __builtin_amdgcn_readfirstlane(offsets[wave]);
    int s1 = __builtin_amdgcn_readfirstlane(offsets[wave + 1]);
    if (s0 < 0) s0 = 0;
    if (s1 > E) s1 = E;
    if (s1 < s0) s1 = s0;
    float ax = 0.f, ay = 0.f;
    for (int i = s0; i < s1; i += 8) {
        unsigned short v[8];
        float m[8];
        #pragma unroll
        for (int k = 0; k < 8; k++) {
            int p = i + k;
            bool val = p < s1;                    // wave-uniform
            int s = val ? __builtin_nontemporal_load(sorted_src + p) : 0;
            int ix = ((unsigned)s < (unsigned)N) ? s : 0;
            m[k] = val ? 1.0f : 0.0f;
            v[k] = *(const unsigned short*)(feat8 + (size_t)ix * DIM + lane * 2);
        }
        #pragma unroll
        for (int k = 0; k < 8; k++) {
            ax = fmaf(m[k], fp82f((unsigned char)(v[k] & 0xFF)), ax);
            ay = fmaf(m[k], fp82f((unsigned char)(v[k] >> 8)), ay);
        }
    }
    unsigned p = (unsigned)f2b(ax) | ((unsigned)f2b(ay) << 16);
    __builtin_nontemporal_store(p, (unsigned*)(agg + (size_t)wave * DIM + lane * 2));
}

// D: out = relu(0.5*norm*(agg @ W^T) + 0.5*init/deg + 0.5*feat)
// OPERAND-SWAPPED: D = W_tile x agg^T, so D col = node m (lane&15) and
// D row = feature j ((lane>>4)*4+reg) -> each lane's f32x4 holds 4
// consecutive features of one node -> pure float4 epilogue, no LDS.
__global__ __launch_bounds__(256) void gemm_ep_k(const unsigned short* __restrict__ agg,
                                                 const unsigned short* __restrict__ wb,
                                                 const int* __restrict__ deg,
                                                 const float* __restrict__ feat,
                                                 const float* __restrict__ init,
                                                 float* __restrict__ out, int N) {
    int wid = threadIdx.x >> 6;
    int lane = threadIdx.x & 63;
    int row16 = lane & 15;              // node within wave tile / W row within j-tile
    int kb = lane >> 4;                 // 0..3, k block of 8
    int base_m = blockIdx.x * 64 + wid * 16;

    // B fragments: agg rows (B col = lane&15 = node, k = kb*8+i)
    short8v bfr[4];
    {
        int m = base_m + row16;
        if (m >= N) m = N - 1;          // clamp; store is masked
        const short8v* ap = (const short8v*)(agg + (size_t)m * DIM);
        #pragma unroll
        for (int ks = 0; ks < 4; ks++) bfr[ks] = ap[ks * 4 + kb];
    }

    f32x4 acc[8] = {};
    #pragma unroll
    for (int ct = 0; ct < 8; ct++) {
        int j = ct * 16 + row16;        // A row = W row j
        const short8v* wp = (const short8v*)(wb + (size_t)j * DIM);
        #pragma unroll
        for (int ks = 0; ks < 4; ks++) {
            short8v afr = wp[ks * 4 + kb];
            acc[ct] = __builtin_amdgcn_mfma_f32_16x16x32_bf16(afr, bfr[ks], acc[ct], 0, 0, 0);
        }
    }

    // epilogue: lane owns node m = base_m + (lane&15), features
    // j = ct*16 + (lane>>4)*4 + r  (r = reg index -> consecutive)
    int m = base_m + row16;
    if (m < N) {
        int dgi = deg[m];
        float dg = (float)(dgi < 1 ? 1 : dgi);
        float nrm = rsqrtf(dg);
        float n1 = 1.0f / dg;
        int jb = (lane >> 4) * 4;
        const float* fp = feat + (size_t)m * DIM;
        const float* ip = init + (size_t)m * DIM;
        float*       op = out  + (size_t)m * DIM;
        #pragma unroll
        for (int ct = 0; ct < 8; ct++) {
            int j = ct * 16 + jb;
            float4 fv = *(const float4*)(fp + j);
            float4 iv = *(const float4*)(ip + j);
            float4 o;
            o.x = fmaxf(0.5f * nrm * acc[ct][0] + 0.5f * n1 * iv.x + 0.5f * fv.x, 0.f);
            o.y = fmaxf(0.5f * nrm * acc[ct][1] + 0.5f * n1 * iv.y + 0.5f * fv.y, 0.f);
            o.z = fmaxf(0.5f * nrm * acc[ct][2] + 0.5f * n1 * iv.z + 0.5f * fv.z, 0.f);
            o.w = fmaxf(0.5f * nrm * acc[ct][3] + 0.5f * n1 * iv.w + 0.5f * fv.w, 0.f);
            *(float4*)(op + j) = o;
        }
    }
}

extern "C" void kernel_launch(void* const* d_in, const int* in_sizes, int n_in,
                              void* d_out, int out_size, void* d_ws, size_t ws_size,
                              hipStream_t stream) {
    const float* feat = (const float*)d_in[0];
    const float* init = (const float*)d_in[1];
    const float* W    = (const float*)d_in[2];
    const int*   src  = (const int*)d_in[3];
    const int*   dst  = (const int*)d_in[4];
    const int N = in_sizes[0] / DIM;
    const int E = in_sizes[3];
    float* out = (float*)d_out;
    const int NB  = (N + BN - 1) / BN;                   // 782 for N=100000
    const int NL1 = (N + (1 << L1BITS) - 1) >> L1BITS;   // 13

    char* ws = (char*)d_ws;
    size_t o_deg = 0;
    size_t o_gc  = o_deg + (size_t)N * 4;
    size_t o_gc1 = o_gc + (size_t)MAXNB * 4;
    size_t o_bb  = o_gc1 + (size_t)MAXL1 * 4;
    size_t o_off = o_bb + (size_t)MAXNB * 4;
    size_t o_srt = (o_off + (size_t)(N + 1) * 4 + 127) & ~(size_t)127;
    size_t o_fs  = (o_srt + (size_t)E * 4 + 511) & ~(size_t)511;
    size_t o_agg = o_fs + (size_t)N * DIM;               // feat8 = N*128 bytes
    size_t o_w   = o_agg + (size_t)N * DIM * 2;
    int*            deg    = (int*)(ws + o_deg);
    int*            gcur   = (int*)(ws + o_gc);
    int*            gcur1  = (int*)(ws + o_gc1);
    int*            bbase  = (int*)(ws + o_bb);
    int*            offsets= (int*)(ws + o_off);
    int*            srt    = (int*)(ws + o_srt);
    unsigned char*  feat8  = (unsigned char*)(ws + o_fs);
    unsigned short* agg    = (unsigned short*)(ws + o_agg);
    unsigned short* wb     = (unsigned short*)(ws + o_w);
    // pairs (12.6MB) + l1 (9.4MB) alias the 25.6MB agg region (both fully
    // consumed by bucket_csr_k before aggregate_k writes agg)
    int*            pairs  = (int*)(ws + o_agg);
    int*            l1     = (int*)(ws + o_agg + (size_t)MAXNB * CAP * 4);

    hipMemsetAsync(gcur, 0, (size_t)(MAXNB + MAXL1) * 4, stream);  // gcur+gcur1

    int p1b = (E + 256 * C1 - 1) / (256 * C1);
    part1_k<<<p1b, 256, 0, stream>>>(src, dst, gcur1, l1, E, NL1);
    part2_k<<<NL1 * NCHK, 256, 0, stream>>>(l1, gcur1, gcur, pairs);
    scan_gcur_k<<<1, 1024, 0, stream>>>(gcur, bbase, NB, offsets, N);
    bucket_csr_k<<<NB, 256, 0, stream>>>(pairs, gcur, bbase, deg, offsets, srt, N, E);

    prep_w_k<<<(DIM * DIM + 255) / 256, 256, 0, stream>>>(W, wb);
    prescale_k<<<(N * (DIM / 4) + 255) / 256, 256, 0, stream>>>(feat, deg, feat8, N);
    aggregate_k<<<(int)(((size_t)N * 64 + 255) / 256), 256, 0, stream>>>(
        feat8, offsets, srt, agg, N, E);
    gemm_ep_k<<<(N + 63) / 64, 256, 0, stream>>>(agg, wb, deg, feat, init, out, N);
}

// Round 20
// 156.054 us; speedup vs baseline: 1.0398x; 1.0398x over previous
//
#include <hip/hip_runtime.h>
#include <hip/hip_fp8.h>

// VGCN layer (R20 = R13 proven pipeline + 16-deep aggregate batch):
//   A1/A2/B: two-level scatter-free CSR build (proven)
//   C : wave-per-node gather, wave-uniform masked 16-DEEP fp8 pipeline.
//       R13-R19 evidence: aggregate is serial-latency-chain bound
//       (idx batch ~500cyc -> dependent gather ~600cyc per 8 edges);
//       16-deep covers mean deg=16 in ~1.5 round trips instead of 2.2.
//   D : bf16 MFMA GEMM, R13 form verbatim (55us; 4 epilogue variants all
//       landed 55-66 -> streaming-rate floor, style-insensitive)

#define DIM 128
#define BN 128            // nodes per fine bucket
#define MAXNB 1024        // max fine buckets
#define CAP 3072          // fine-bucket capacity (mean ~2048, sigma ~45)
#define L1BITS 13         // L1 bucket = 8192 nodes
#define MAXL1 16
#define CAP1 147456       // L1 capacity (mean 131072, sigma ~347) = 72*2048
#define NCHK 72           // part2 chunks per L1 bucket (NCHK*2048 == CAP1)
#define C1 8              // edges/thread, phase A1
#define C2 8              // edges/thread, phase A2

typedef __attribute__((ext_vector_type(8))) short short8v;   // 8 bf16
typedef __attribute__((ext_vector_type(4))) float f32x4;     // MFMA acc

static __device__ __forceinline__ unsigned short f2b(float f) {
    unsigned u = __float_as_uint(f);
    unsigned r = (u >> 16) & 1;          // round-to-nearest-even
    u += 0x7fffu + r;
    return (unsigned short)(u >> 16);
}

static __device__ __forceinline__ unsigned char f2fp8(float f) {
    __hip_fp8_e4m3 h(f);                 // OCP e4m3fn, HW convert on gfx950
    return h.__x;
}
static __device__ __forceinline__ float fp82f(unsigned char b) {
    __hip_fp8_e4m3 h; h.__x = b;
    return (float)h;
}

// A1: 13-bin partition, coalesced appends of packed (dst&8191)<<17|src
__global__ __launch_bounds__(256) void part1_k(const int* __restrict__ src,
                                               const int* __restrict__ dst,
                                               int* __restrict__ gcur1,
                                               int* __restrict__ l1,
                                               int E, int NL1) {
    __shared__ int stage[256 * C1];
    __shared__ int hist[MAXL1], excl[MAXL1], gbase[MAXL1];
    int tid = threadIdx.x, lane = tid & 63, wid = tid >> 6;
    int e0 = blockIdx.x * 256 * C1;
    int bk[C1], pk[C1];
    #pragma unroll
    for (int k = 0; k < C1; k++) {
        int e = e0 + k * 256 + tid;
        bool valid = e < E;
        int d = valid ? __builtin_nontemporal_load(dst + e) : 0;
        int s = valid ? __builtin_nontemporal_load(src + e) : 0;
        bk[k] = valid ? (d >> L1BITS) : -1;
        pk[k] = ((d & 8191) << 17) | s;
    }
    if (tid < MAXL1) hist[tid] = 0;
    __syncthreads();
    #pragma unroll
    for (int k = 0; k < C1; k++)
        if (bk[k] >= 0) atomicAdd(&hist[bk[k]], 1);
    __syncthreads();
    if (tid == 0) { int run = 0; for (int b = 0; b < NL1; b++) { excl[b] = run; run += hist[b]; } }
    __syncthreads();
    if (tid < MAXL1) hist[tid] = 0;              // reuse as cursor
    __syncthreads();
    #pragma unroll
    for (int k = 0; k < C1; k++)
        if (bk[k] >= 0) {
            int pos = excl[bk[k]] + atomicAdd(&hist[bk[k]], 1);
            stage[pos] = pk[k];
        }
    __syncthreads();
    if (tid < NL1) { int c = hist[tid]; gbase[tid] = c ? atomicAdd(&gcur1[tid], c) : 0; }
    __syncthreads();
    for (int b = wid; b < NL1; b += 4) {
        int c = hist[b], eo = excl[b], gb = gbase[b];
        int cw = c;                                   // partial flush on overflow
        if (gb >= CAP1) cw = 0;
        else if (gb + cw > CAP1) cw = CAP1 - gb;
        if (cw > 0) {
            int* dp = l1 + (size_t)b * CAP1 + gb;
            for (int i = lane; i < cw; i += 64)
                __builtin_nontemporal_store(stage[eo + i], dp + i);
        }
    }
}

// A2: split each L1 list into NCHK chunks of 2048; 64-bin partition into fine
// buckets. fine-local id = (v>>24)&63; repack = v & 0xFFFFFF.
__global__ __launch_bounds__(256) void part2_k(const int* __restrict__ l1,
                                               const int* __restrict__ gcur1,
                                               int* __restrict__ gcur,
                                               int* __restrict__ pairs) {
    __shared__ int stage[256 * C2];
    __shared__ int hist[64], excl[64], gbase[64];
    int tid = threadIdx.x, lane = tid & 63, wid = tid >> 6;
    int b1 = blockIdx.x / NCHK, q = blockIdx.x % NCHK;
    int cnt = gcur1[b1];
    if (cnt < 0) cnt = 0;
    if (cnt > CAP1) cnt = CAP1;
    int start = q * 256 * C2;
    const int* pl = l1 + (size_t)b1 * CAP1;
    int bk[C2], pk[C2];
    #pragma unroll
    for (int k = 0; k < C2; k++) {
        int i = start + k * 256 + tid;
        bool valid = i < cnt;
        int v = valid ? __builtin_nontemporal_load(pl + i) : 0;
        bk[k] = valid ? ((v >> 24) & 63) : -1;
        pk[k] = v & 0xFFFFFF;
    }
    if (tid < 64) hist[tid] = 0;
    __syncthreads();
    #pragma unroll
    for (int k = 0; k < C2; k++)
        if (bk[k] >= 0) atomicAdd(&hist[bk[k]], 1);
    __syncthreads();
    if (wid == 0) {                               // wave-0 scan of 64 bins
        int v = hist[lane];
        int sc = v;
        #pragma unroll
        for (int o = 1; o < 64; o <<= 1) {
            int t = __shfl_up(sc, o);
            if (lane >= o) sc += t;
        }
        excl[lane] = sc - v;
    }
    __syncthreads();
    if (tid < 64) hist[tid] = 0;                  // reuse as cursor
    __syncthreads();
    #pragma unroll
    for (int k = 0; k < C2; k++)
        if (bk[k] >= 0) {
            int pos = excl[bk[k]] + atomicAdd(&hist[bk[k]], 1);
            stage[pos] = pk[k];
        }
    __syncthreads();
    if (tid < 64) {
        int c = hist[tid];
        gbase[tid] = c ? atomicAdd(&gcur[(b1 << 6) + tid], c) : 0;
    }
    __syncthreads();
    for (int b = wid; b < 64; b += 4) {
        int c = hist[b], eo = excl[b], gb = gbase[b];
        int cw = c;                                   // partial flush on overflow
        if (gb >= CAP) cw = 0;
        else if (gb + cw > CAP) cw = CAP - gb;
        if (cw > 0) {
            int* dp = pairs + (size_t)((b1 << 6) + b) * CAP + gb;
            for (int i = lane; i < cw; i += 64)
                __builtin_nontemporal_store(stage[eo + i], dp + i);
        }
    }
}

// exclusive scan of CLAMPED gcur (NB <= 1024) -> bbase; offsets[N] = total
__global__ __launch_bounds__(1024) void scan_gcur_k(const int* __restrict__ gcur,
                                                    int* __restrict__ bbase, int NB,
                                                    int* __restrict__ offsets, int N) {
    __shared__ int sh[1024];
    int t = threadIdx.x;
    int v = 0;
    if (t < NB) {
        v = gcur[t];
        if (v < 0) v = 0;
        if (v > CAP) v = CAP;
    }
    sh[t] = v;
    __syncthreads();
    for (int off = 1; off < 1024; off <<= 1) {
        int u = (t >= off) ? sh[t - off] : 0;
        __syncthreads();
        sh[t] += u;
        __syncthreads();
    }
    if (t < NB) bbase[t] = sh[t] - v;
    if (t == NB - 1) offsets[N] = sh[t];          // scanned total (== E normally)
}

// B: per-bucket counting sort in LDS; deg/offsets/sorted_src all coalesced.
__global__ __launch_bounds__(256) void bucket_csr_k(const int* __restrict__ pairs,
                                                    const int* __restrict__ gcur,
                                                    const int* __restrict__ bbase,
                                                    int* __restrict__ deg,
                                                    int* __restrict__ offsets,
                                                    int* __restrict__ sorted_src,
                                                    int N, int E) {
    __shared__ int pbuf[CAP];
    __shared__ int sbuf[CAP];
    __shared__ int hist[BN];
    __shared__ int excl[BN];
    __shared__ int cur[BN];
    int b = blockIdx.x, tid = threadIdx.x;
    int cnt = gcur[b];
    if (cnt < 0) cnt = 0;
    if (cnt > CAP) cnt = CAP;
    int base = bbase[b];
    if (base < 0) base = 0;
    if (base > E) base = E;
    if (base + cnt > E) cnt = E - base;          // never write past sorted_src[E]
    const int* pl = pairs + (size_t)b * CAP;
    for (int i = tid; i < cnt; i += 256) pbuf[i] = pl[i];
    if (tid < BN) { hist[tid] = 0; cur[tid] = 0; }
    __syncthreads();
    for (int i = tid; i < cnt; i += 256) atomicAdd(&hist[pbuf[i] >> 17], 1);
    __syncthreads();
    if (tid < BN) excl[tid] = hist[tid];
    __syncthreads();
    for (int off = 1; off < BN; off <<= 1) {         // Hillis-Steele inclusive
        int u = (tid < BN && tid >= off) ? excl[tid - off] : 0;
        __syncthreads();
        if (tid < BN) excl[tid] += u;
        __syncthreads();
    }
    if (tid < BN) excl[tid] -= hist[tid];            // -> exclusive
    __syncthreads();
    int nloc = N - b * BN; if (nloc > BN) nloc = BN;
    if (tid < nloc) {
        deg[b * BN + tid] = hist[tid];
        offsets[b * BN + tid] = base + excl[tid];
    }
    for (int i = tid; i < cnt; i += 256) {
        int v = pbuf[i];
        int pos = excl[v >> 17] + atomicAdd(&cur[v >> 17], 1);
        if (pos >= 0 && pos < CAP) sbuf[pos] = v & 0x1ffff;
    }
    __syncthreads();
    int* dp = sorted_src + base;
    for (int i = tid; i < cnt; i += 256) dp[i] = sbuf[i];
}

// W (fp32 row-major [j][k]) -> bf16
__global__ __launch_bounds__(256) void prep_w_k(const float* __restrict__ W,
                                                unsigned short* __restrict__ wb) {
    int i = blockIdx.x * 256 + threadIdx.x;
    if (i < DIM * DIM) wb[i] = f2b(W[i]);
}

// feat8[n][k] = fp8_e4m3(deg[n]^-1/2 * feat[n][k]); one thread per 4 elems
__global__ __launch_bounds__(256) void prescale_k(const float* __restrict__ feat,
                                                  const int* __restrict__ deg,
                                                  unsigned char* __restrict__ feat8,
                                                  int N) {
    int idx = blockIdx.x * 256 + threadIdx.x;
    int total = N * (DIM / 4);
    if (idx >= total) return;
    int n = idx >> 5;
    int dgi = deg[n];
    float dg = (float)(dgi < 1 ? 1 : dgi);
    float nrm = rsqrtf(dg);
    float4 f = ((const float4*)feat)[idx];
    unsigned v = (unsigned)f2fp8(f.x * nrm)
               | ((unsigned)f2fp8(f.y * nrm) << 8)
               | ((unsigned)f2fp8(f.z * nrm) << 16)
               | ((unsigned)f2fp8(f.w * nrm) << 24);
    ((unsigned*)feat8)[idx] = v;
}

// C: one wave per node; wave-uniform masked 16-deep gather over fp8 rows
// (128B/row, one coalesced row per load instruction).
__global__ __launch_bounds__(256) void aggregate_k(const unsigned char* __restrict__ feat8,
                                                   const int* __restrict__ offsets,
                                                   const int* __restrict__ sorted_src,
                                                   unsigned short* __restrict__ agg,
                                                   int N, int E) {
    int wave = (blockIdx.x * 256 + threadIdx.x) >> 6;
    int lane = threadIdx.x & 63;
    if (wave >= N) return;
    int s0 = __builtin_amdgcn_readfirstlane(offsets[wave]);
    int s1 = __builtin_amdgcn_readfirstlane(offsets[wave + 1]);
    if (s0 < 0) s0 = 0;
    if (s1 > E) s1 = E;
    if (s1 < s0) s1 = s0;
    float ax = 0.f, ay = 0.f;
    for (int i = s0; i < s1; i += 16) {
        unsigned short v[16];
        float m[16];
        // batch 1: issue all 16 idx loads, then all 16 row gathers
        #pragma unroll
        for (int k = 0; k < 16; k++) {
            int p = i + k;
            bool val = p < s1;                    // wave-uniform
            int s = val ? __builtin_nontemporal_load(sorted_src + p) : 0;
            int ix = ((unsigned)s < (unsigned)N) ? s : 0;
            m[k] = val ? 1.0f : 0.0f;
            v[k] = *(const unsigned short*)(feat8 + (size_t)ix * DIM + lane * 2);
        }
        #pragma unroll
        for (int k = 0; k < 16; k++) {
            ax = fmaf(m[k], fp82f((unsigned char)(v[k] & 0xFF)), ax);
            ay = fmaf(m[k], fp82f((unsigned char)(v[k] >> 8)), ay);
        }
    }
    unsigned p = (unsigned)f2b(ax) | ((unsigned)f2b(ay) << 16);
    __builtin_nontemporal_store(p, (unsigned*)(agg + (size_t)wave * DIM + lane * 2));
}

// D: out = relu(0.5*norm*(agg @ W^T) + 0.5*init/deg + 0.5*feat)  [R13 form]
__global__ __launch_bounds__(256) void gemm_ep_k(const unsigned short* __restrict__ agg,
                                                 const unsigned short* __restrict__ wb,
                                                 const int* __restrict__ deg,
                                                 const float* __restrict__ feat,
                                                 const float* __restrict__ init,
                                                 float* __restrict__ out, int N) {
    int wid = threadIdx.x >> 6;
    int lane = threadIdx.x & 63;
    int row16 = lane & 15;
    int kb = lane >> 4;                 // 0..3, k block of 8
    int base_m = blockIdx.x * 128 + wid * 32;

    short8v afr[2][4];
    #pragma unroll
    for (int mt = 0; mt < 2; mt++) {
        int m = base_m + mt * 16 + row16;
        if (m >= N) m = N - 1;          // clamp; store is masked
        const short8v* ap = (const short8v*)(agg + (size_t)m * DIM);
        #pragma unroll
        for (int ks = 0; ks < 4; ks++) afr[mt][ks] = ap[ks * 4 + kb];
    }

    f32x4 acc[2][8] = {};
    #pragma unroll
    for (int ct = 0; ct < 8; ct++) {
        int j = ct * 16 + row16;        // B col = W row (B = W^T)
        const short8v* bp = (const short8v*)(wb + (size_t)j * DIM);
        #pragma unroll
        for (int ks = 0; ks < 4; ks++) {
            short8v bfr = bp[ks * 4 + kb];
            acc[0][ct] = __builtin_amdgcn_mfma_f32_16x16x32_bf16(afr[0][ks], bfr, acc[0][ct], 0, 0, 0);
            acc[1][ct] = __builtin_amdgcn_mfma_f32_16x16x32_bf16(afr[1][ks], bfr, acc[1][ct], 0, 0, 0);
        }
    }

    // epilogue: D layout col=lane&15, row=(lane>>4)*4+reg
    #pragma unroll
    for (int mt = 0; mt < 2; mt++) {
        int m0 = base_m + mt * 16 + (lane >> 4) * 4;
        #pragma unroll
        for (int r = 0; r < 4; r++) {
            int m = m0 + r;
            if (m >= N) continue;
            int dgi = deg[m];
            float dg = (float)(dgi < 1 ? 1 : dgi);
            float nrm = rsqrtf(dg);
            float n1 = 1.0f / dg;
            #pragma unroll
            for (int ct = 0; ct < 8; ct++) {
                int j = ct * 16 + row16;
                float o = 0.5f * nrm * acc[mt][ct][r]
                        + 0.5f * n1 * init[(size_t)m * DIM + j]
                        + 0.5f * feat[(size_t)m * DIM + j];
                out[(size_t)m * DIM + j] = fmaxf(o, 0.f);
            }
        }
    }
}

extern "C" void kernel_launch(void* const* d_in, const int* in_sizes, int n_in,
                              void* d_out, int out_size, void* d_ws, size_t ws_size,
                              hipStream_t stream) {
    const float* feat = (const float*)d_in[0];
    const float* init = (const float*)d_in[1];
    const float* W    = (const float*)d_in[2];
    const int*   src  = (const int*)d_in[3];
    const int*   dst  = (const int*)d_in[4];
    const int N = in_sizes[0] / DIM;
    const int E = in_sizes[3];
    float* out = (float*)d_out;
    const int NB  = (N + BN - 1) / BN;                   // 782 for N=100000
    const int NL1 = (N + (1 << L1BITS) - 1) >> L1BITS;   // 13

    char* ws = (char*)d_ws;
    size_t o_deg = 0;
    size_t o_gc  = o_deg + (size_t)N * 4;
    size_t o_gc1 = o_gc + (size_t)MAXNB * 4;
    size_t o_bb  = o_gc1 + (size_t)MAXL1 * 4;
    size_t o_off = o_bb + (size_t)MAXNB * 4;
    size_t o_srt = (o_off + (size_t)(N + 1) * 4 + 127) & ~(size_t)127;
    size_t o_fs  = (o_srt + (size_t)E * 4 + 511) & ~(size_t)511;
    size_t o_agg = o_fs + (size_t)N * DIM;               // feat8 = N*128 bytes
    size_t o_w   = o_agg + (size_t)N * DIM * 2;
    int*            deg    = (int*)(ws + o_deg);
    int*            gcur   = (int*)(ws + o_gc);
    int*            gcur1  = (int*)(ws + o_gc1);
    int*            bbase  = (int*)(ws + o_bb);
    int*            offsets= (int*)(ws + o_off);
    int*            srt    = (int*)(ws + o_srt);
    unsigned char*  feat8  = (unsigned char*)(ws + o_fs);
    unsigned short* agg    = (unsigned short*)(ws + o_agg);
    unsigned short* wb     = (unsigned short*)(ws + o_w);
    // pairs (12.6MB) + l1 (9.4MB) alias the 25.6MB agg region (both fully
    // consumed by bucket_csr_k before aggregate_k writes agg)
    int*            pairs  = (int*)(ws + o_agg);
    int*            l1     = (int*)(ws + o_agg + (size_t)MAXNB * CAP * 4);

    hipMemsetAsync(gcur, 0, (size_t)(MAXNB + MAXL1) * 4, stream);  // gcur+gcur1

    int p1b = (E + 256 * C1 - 1) / (256 * C1);
    part1_k<<<p1b, 256, 0, stream>>>(src, dst, gcur1, l1, E, NL1);
    part2_k<<<NL1 * NCHK, 256, 0, stream>>>(l1, gcur1, gcur, pairs);
    scan_gcur_k<<<1, 1024, 0, stream>>>(gcur, bbase, NB, offsets, N);
    bucket_csr_k<<<NB, 256, 0, stream>>>(pairs, gcur, bbase, deg, offsets, srt, N, E);

    prep_w_k<<<(DIM * DIM + 255) / 256, 256, 0, stream>>>(W, wb);
    prescale_k<<<(N * (DIM / 4) + 255) / 256, 256, 0, stream>>>(feat, deg, feat8, N);
    aggregate_k<<<(int)(((size_t)N * 64 + 255) / 256), 256, 0, stream>>>(
        feat8, offsets, srt, agg, N, E);
    gemm_ep_k<<<(N + 127) / 128, 256, 0, stream>>>(agg, wb, deg, feat, init, out, N);
}

// Round 21
// 151.298 us; speedup vs baseline: 1.0725x; 1.0314x over previous
//
#include <hip/hip_runtime.h>
#include <hip/hip_fp8.h>

// VGCN layer (R21 = the proven optimum, R13 configuration):
//   A1/A2/B: two-level scatter-free CSR build
//   C : wave-per-node gather, wave-uniform masked 8-DEEP fp8 pipeline
//       (8-deep is the measured optimum: paired/16-deep/nt variants all lost)
//   D : bf16 MFMA GEMM, scalar epilogue (measured optimum among 4 variants)
// Floors (measured over R13-R20): aggregate ~55us (L3 random-line rate),
// gemm ~55us (streaming-mix rate), CSR build ~40us (coalesced streaming).

#define DIM 128
#define BN 128            // nodes per fine bucket
#define MAXNB 1024        // max fine buckets
#define CAP 3072          // fine-bucket capacity (mean ~2048, sigma ~45)
#define L1BITS 13         // L1 bucket = 8192 nodes
#define MAXL1 16
#define CAP1 147456       // L1 capacity (mean 131072, sigma ~347) = 72*2048
#define NCHK 72           // part2 chunks per L1 bucket (NCHK*2048 == CAP1)
#define C1 8              // edges/thread, phase A1
#define C2 8              // edges/thread, phase A2

typedef __attribute__((ext_vector_type(8))) short short8v;   // 8 bf16
typedef __attribute__((ext_vector_type(4))) float f32x4;     // MFMA acc

static __device__ __forceinline__ unsigned short f2b(float f) {
    unsigned u = __float_as_uint(f);
    unsigned r = (u >> 16) & 1;          // round-to-nearest-even
    u += 0x7fffu + r;
    return (unsigned short)(u >> 16);
}

static __device__ __forceinline__ unsigned char f2fp8(float f) {
    __hip_fp8_e4m3 h(f);                 // OCP e4m3fn, HW convert on gfx950
    return h.__x;
}
static __device__ __forceinline__ float fp82f(unsigned char b) {
    __hip_fp8_e4m3 h; h.__x = b;
    return (float)h;
}

// A1: 13-bin partition, coalesced appends of packed (dst&8191)<<17|src
__global__ __launch_bounds__(256) void part1_k(const int* __restrict__ src,
                                               const int* __restrict__ dst,
                                               int* __restrict__ gcur1,
                                               int* __restrict__ l1,
                                               int E, int NL1) {
    __shared__ int stage[256 * C1];
    __shared__ int hist[MAXL1], excl[MAXL1], gbase[MAXL1];
    int tid = threadIdx.x, lane = tid & 63, wid = tid >> 6;
    int e0 = blockIdx.x * 256 * C1;
    int bk[C1], pk[C1];
    #pragma unroll
    for (int k = 0; k < C1; k++) {
        int e = e0 + k * 256 + tid;
        bool valid = e < E;
        int d = valid ? __builtin_nontemporal_load(dst + e) : 0;
        int s = valid ? __builtin_nontemporal_load(src + e) : 0;
        bk[k] = valid ? (d >> L1BITS) : -1;
        pk[k] = ((d & 8191) << 17) | s;
    }
    if (tid < MAXL1) hist[tid] = 0;
    __syncthreads();
    #pragma unroll
    for (int k = 0; k < C1; k++)
        if (bk[k] >= 0) atomicAdd(&hist[bk[k]], 1);
    __syncthreads();
    if (tid == 0) { int run = 0; for (int b = 0; b < NL1; b++) { excl[b] = run; run += hist[b]; } }
    __syncthreads();
    if (tid < MAXL1) hist[tid] = 0;              // reuse as cursor
    __syncthreads();
    #pragma unroll
    for (int k = 0; k < C1; k++)
        if (bk[k] >= 0) {
            int pos = excl[bk[k]] + atomicAdd(&hist[bk[k]], 1);
            stage[pos] = pk[k];
        }
    __syncthreads();
    if (tid < NL1) { int c = hist[tid]; gbase[tid] = c ? atomicAdd(&gcur1[tid], c) : 0; }
    __syncthreads();
    for (int b = wid; b < NL1; b += 4) {
        int c = hist[b], eo = excl[b], gb = gbase[b];
        int cw = c;                                   // partial flush on overflow
        if (gb >= CAP1) cw = 0;
        else if (gb + cw > CAP1) cw = CAP1 - gb;
        if (cw > 0) {
            int* dp = l1 + (size_t)b * CAP1 + gb;
            for (int i = lane; i < cw; i += 64)
                __builtin_nontemporal_store(stage[eo + i], dp + i);
        }
    }
}

// A2: split each L1 list into NCHK chunks of 2048; 64-bin partition into fine
// buckets. fine-local id = (v>>24)&63; repack = v & 0xFFFFFF.
__global__ __launch_bounds__(256) void part2_k(const int* __restrict__ l1,
                                               const int* __restrict__ gcur1,
                                               int* __restrict__ gcur,
                                               int* __restrict__ pairs) {
    __shared__ int stage[256 * C2];
    __shared__ int hist[64], excl[64], gbase[64];
    int tid = threadIdx.x, lane = tid & 63, wid = tid >> 6;
    int b1 = blockIdx.x / NCHK, q = blockIdx.x % NCHK;
    int cnt = gcur1[b1];
    if (cnt < 0) cnt = 0;
    if (cnt > CAP1) cnt = CAP1;
    int start = q * 256 * C2;
    const int* pl = l1 + (size_t)b1 * CAP1;
    int bk[C2], pk[C2];
    #pragma unroll
    for (int k = 0; k < C2; k++) {
        int i = start + k * 256 + tid;
        bool valid = i < cnt;
        int v = valid ? __builtin_nontemporal_load(pl + i) : 0;
        bk[k] = valid ? ((v >> 24) & 63) : -1;
        pk[k] = v & 0xFFFFFF;
    }
    if (tid < 64) hist[tid] = 0;
    __syncthreads();
    #pragma unroll
    for (int k = 0; k < C2; k++)
        if (bk[k] >= 0) atomicAdd(&hist[bk[k]], 1);
    __syncthreads();
    if (wid == 0) {                               // wave-0 scan of 64 bins
        int v = hist[lane];
        int sc = v;
        #pragma unroll
        for (int o = 1; o < 64; o <<= 1) {
            int t = __shfl_up(sc, o);
            if (lane >= o) sc += t;
        }
        excl[lane] = sc - v;
    }
    __syncthreads();
    if (tid < 64) hist[tid] = 0;                  // reuse as cursor
    __syncthreads();
    #pragma unroll
    for (int k = 0; k < C2; k++)
        if (bk[k] >= 0) {
            int pos = excl[bk[k]] + atomicAdd(&hist[bk[k]], 1);
            stage[pos] = pk[k];
        }
    __syncthreads();
    if (tid < 64) {
        int c = hist[tid];
        gbase[tid] = c ? atomicAdd(&gcur[(b1 << 6) + tid], c) : 0;
    }
    __syncthreads();
    for (int b = wid; b < 64; b += 4) {
        int c = hist[b], eo = excl[b], gb = gbase[b];
        int cw = c;                                   // partial flush on overflow
        if (gb >= CAP) cw = 0;
        else if (gb + cw > CAP) cw = CAP - gb;
        if (cw > 0) {
            int* dp = pairs + (size_t)((b1 << 6) + b) * CAP + gb;
            for (int i = lane; i < cw; i += 64)
                __builtin_nontemporal_store(stage[eo + i], dp + i);
        }
    }
}

// exclusive scan of CLAMPED gcur (NB <= 1024) -> bbase; offsets[N] = total
__global__ __launch_bounds__(1024) void scan_gcur_k(const int* __restrict__ gcur,
                                                    int* __restrict__ bbase, int NB,
                                                    int* __restrict__ offsets, int N) {
    __shared__ int sh[1024];
    int t = threadIdx.x;
    int v = 0;
    if (t < NB) {
        v = gcur[t];
        if (v < 0) v = 0;
        if (v > CAP) v = CAP;
    }
    sh[t] = v;
    __syncthreads();
    for (int off = 1; off < 1024; off <<= 1) {
        int u = (t >= off) ? sh[t - off] : 0;
        __syncthreads();
        sh[t] += u;
        __syncthreads();
    }
    if (t < NB) bbase[t] = sh[t] - v;
    if (t == NB - 1) offsets[N] = sh[t];          // scanned total (== E normally)
}

// B: per-bucket counting sort in LDS; deg/offsets/sorted_src all coalesced.
__global__ __launch_bounds__(256) void bucket_csr_k(const int* __restrict__ pairs,
                                                    const int* __restrict__ gcur,
                                                    const int* __restrict__ bbase,
                                                    int* __restrict__ deg,
                                                    int* __restrict__ offsets,
                                                    int* __restrict__ sorted_src,
                                                    int N, int E) {
    __shared__ int pbuf[CAP];
    __shared__ int sbuf[CAP];
    __shared__ int hist[BN];
    __shared__ int excl[BN];
    __shared__ int cur[BN];
    int b = blockIdx.x, tid = threadIdx.x;
    int cnt = gcur[b];
    if (cnt < 0) cnt = 0;
    if (cnt > CAP) cnt = CAP;
    int base = bbase[b];
    if (base < 0) base = 0;
    if (base > E) base = E;
    if (base + cnt > E) cnt = E - base;          // never write past sorted_src[E]
    const int* pl = pairs + (size_t)b * CAP;
    for (int i = tid; i < cnt; i += 256) pbuf[i] = pl[i];
    if (tid < BN) { hist[tid] = 0; cur[tid] = 0; }
    __syncthreads();
    for (int i = tid; i < cnt; i += 256) atomicAdd(&hist[pbuf[i] >> 17], 1);
    __syncthreads();
    if (tid < BN) excl[tid] = hist[tid];
    __syncthreads();
    for (int off = 1; off < BN; off <<= 1) {         // Hillis-Steele inclusive
        int u = (tid < BN && tid >= off) ? excl[tid - off] : 0;
        __syncthreads();
        if (tid < BN) excl[tid] += u;
        __syncthreads();
    }
    if (tid < BN) excl[tid] -= hist[tid];            // -> exclusive
    __syncthreads();
    int nloc = N - b * BN; if (nloc > BN) nloc = BN;
    if (tid < nloc) {
        deg[b * BN + tid] = hist[tid];
        offsets[b * BN + tid] = base + excl[tid];
    }
    for (int i = tid; i < cnt; i += 256) {
        int v = pbuf[i];
        int pos = excl[v >> 17] + atomicAdd(&cur[v >> 17], 1);
        if (pos >= 0 && pos < CAP) sbuf[pos] = v & 0x1ffff;
    }
    __syncthreads();
    int* dp = sorted_src + base;
    for (int i = tid; i < cnt; i += 256) dp[i] = sbuf[i];
}

// W (fp32 row-major [j][k]) -> bf16
__global__ __launch_bounds__(256) void prep_w_k(const float* __restrict__ W,
                                                unsigned short* __restrict__ wb) {
    int i = blockIdx.x * 256 + threadIdx.x;
    if (i < DIM * DIM) wb[i] = f2b(W[i]);
}

// feat8[n][k] = fp8_e4m3(deg[n]^-1/2 * feat[n][k]); one thread per 4 elems
__global__ __launch_bounds__(256) void prescale_k(const float* __restrict__ feat,
                                                  const int* __restrict__ deg,
                                                  unsigned char* __restrict__ feat8,
                                                  int N) {
    int idx = blockIdx.x * 256 + threadIdx.x;
    int total = N * (DIM / 4);
    if (idx >= total) return;
    int n = idx >> 5;
    int dgi = deg[n];
    float dg = (float)(dgi < 1 ? 1 : dgi);
    float nrm = rsqrtf(dg);
    float4 f = ((const float4*)feat)[idx];
    unsigned v = (unsigned)f2fp8(f.x * nrm)
               | ((unsigned)f2fp8(f.y * nrm) << 8)
               | ((unsigned)f2fp8(f.z * nrm) << 16)
               | ((unsigned)f2fp8(f.w * nrm) << 24);
    ((unsigned*)feat8)[idx] = v;
}

// C: one wave per node; wave-uniform masked 8-deep gather over fp8 rows
// (128B/row, one coalesced row per load instruction). Proven optimum.
__global__ __launch_bounds__(256) void aggregate_k(const unsigned char* __restrict__ feat8,
                                                   const int* __restrict__ offsets,
                                                   const int* __restrict__ sorted_src,
                                                   unsigned short* __restrict__ agg,
                                                   int N, int E) {
    int wave = (blockIdx.x * 256 + threadIdx.x) >> 6;
    int lane = threadIdx.x & 63;
    if (wave >= N) return;
    int s0 = __builtin_amdgcn_readfirstlane(offsets[wave]);
    int s1 = __builtin_amdgcn_readfirstlane(offsets[wave + 1]);
    if (s0 < 0) s0 = 0;
    if (s1 > E) s1 = E;
    if (s1 < s0) s1 = s0;
    float ax = 0.f, ay = 0.f;
    for (int i = s0; i < s1; i += 8) {
        unsigned short v[8];
        float m[8];
        #pragma unroll
        for (int k = 0; k < 8; k++) {
            int p = i + k;
            bool val = p < s1;                    // wave-uniform
            int s = val ? __builtin_nontemporal_load(sorted_src + p) : 0;
            int ix = ((unsigned)s < (unsigned)N) ? s : 0;
            m[k] = val ? 1.0f : 0.0f;
            v[k] = *(const unsigned short*)(feat8 + (size_t)ix * DIM + lane * 2);
        }
        #pragma unroll
        for (int k = 0; k < 8; k++) {
            ax = fmaf(m[k], fp82f((unsigned char)(v[k] & 0xFF)), ax);
            ay = fmaf(m[k], fp82f((unsigned char)(v[k] >> 8)), ay);
        }
    }
    unsigned p = (unsigned)f2b(ax) | ((unsigned)f2b(ay) << 16);
    __builtin_nontemporal_store(p, (unsigned*)(agg + (size_t)wave * DIM + lane * 2));
}

// D: out = relu(0.5*norm*(agg @ W^T) + 0.5*init/deg + 0.5*feat)  [proven form]
__global__ __launch_bounds__(256) void gemm_ep_k(const unsigned short* __restrict__ agg,
                                                 const unsigned short* __restrict__ wb,
                                                 const int* __restrict__ deg,
                                                 const float* __restrict__ feat,
                                                 const float* __restrict__ init,
                                                 float* __restrict__ out, int N) {
    int wid = threadIdx.x >> 6;
    int lane = threadIdx.x & 63;
    int row16 = lane & 15;
    int kb = lane >> 4;                 // 0..3, k block of 8
    int base_m = blockIdx.x * 128 + wid * 32;

    short8v afr[2][4];
    #pragma unroll
    for (int mt = 0; mt < 2; mt++) {
        int m = base_m + mt * 16 + row16;
        if (m >= N) m = N - 1;          // clamp; store is masked
        const short8v* ap = (const short8v*)(agg + (size_t)m * DIM);
        #pragma unroll
        for (int ks = 0; ks < 4; ks++) afr[mt][ks] = ap[ks * 4 + kb];
    }

    f32x4 acc[2][8] = {};
    #pragma unroll
    for (int ct = 0; ct < 8; ct++) {
        int j = ct * 16 + row16;        // B col = W row (B = W^T)
        const short8v* bp = (const short8v*)(wb + (size_t)j * DIM);
        #pragma unroll
        for (int ks = 0; ks < 4; ks++) {
            short8v bfr = bp[ks * 4 + kb];
            acc[0][ct] = __builtin_amdgcn_mfma_f32_16x16x32_bf16(afr[0][ks], bfr, acc[0][ct], 0, 0, 0);
            acc[1][ct] = __builtin_amdgcn_mfma_f32_16x16x32_bf16(afr[1][ks], bfr, acc[1][ct], 0, 0, 0);
        }
    }

    // epilogue: D layout col=lane&15, row=(lane>>4)*4+reg
    #pragma unroll
    for (int mt = 0; mt < 2; mt++) {
        int m0 = base_m + mt * 16 + (lane >> 4) * 4;
        #pragma unroll
        for (int r = 0; r < 4; r++) {
            int m = m0 + r;
            if (m >= N) continue;
            int dgi = deg[m];
            float dg = (float)(dgi < 1 ? 1 : dgi);
            float nrm = rsqrtf(dg);
            float n1 = 1.0f / dg;
            #pragma unroll
            for (int ct = 0; ct < 8; ct++) {
                int j = ct * 16 + row16;
                float o = 0.5f * nrm * acc[mt][ct][r]
                        + 0.5f * n1 * init[(size_t)m * DIM + j]
                        + 0.5f * feat[(size_t)m * DIM + j];
                out[(size_t)m * DIM + j] = fmaxf(o, 0.f);
            }
        }
    }
}

extern "C" void kernel_launch(void* const* d_in, const int* in_sizes, int n_in,
                              void* d_out, int out_size, void* d_ws, size_t ws_size,
                              hipStream_t stream) {
    const float* feat = (const float*)d_in[0];
    const float* init = (const float*)d_in[1];
    const float* W    = (const float*)d_in[2];
    const int*   src  = (const int*)d_in[3];
    const int*   dst  = (const int*)d_in[4];
    const int N = in_sizes[0] / DIM;
    const int E = in_sizes[3];
    float* out = (float*)d_out;
    const int NB  = (N + BN - 1) / BN;                   // 782 for N=100000
    const int NL1 = (N + (1 << L1BITS) - 1) >> L1BITS;   // 13

    char* ws = (char*)d_ws;
    size_t o_deg = 0;
    size_t o_gc  = o_deg + (size_t)N * 4;
    size_t o_gc1 = o_gc + (size_t)MAXNB * 4;
    size_t o_bb  = o_gc1 + (size_t)MAXL1 * 4;
    size_t o_off = o_bb + (size_t)MAXNB * 4;
    size_t o_srt = (o_off + (size_t)(N + 1) * 4 + 127) & ~(size_t)127;
    size_t o_fs  = (o_srt + (size_t)E * 4 + 511) & ~(size_t)511;
    size_t o_agg = o_fs + (size_t)N * DIM;               // feat8 = N*128 bytes
    size_t o_w   = o_agg + (size_t)N * DIM * 2;
    int*            deg    = (int*)(ws + o_deg);
    int*            gcur   = (int*)(ws + o_gc);
    int*            gcur1  = (int*)(ws + o_gc1);
    int*            bbase  = (int*)(ws + o_bb);
    int*            offsets= (int*)(ws + o_off);
    int*            srt    = (int*)(ws + o_srt);
    unsigned char*  feat8  = (unsigned char*)(ws + o_fs);
    unsigned short* agg    = (unsigned short*)(ws + o_agg);
    unsigned short* wb     = (unsigned short*)(ws + o_w);
    // pairs (12.6MB) + l1 (9.4MB) alias the 25.6MB agg region (both fully
    // consumed by bucket_csr_k before aggregate_k writes agg)
    int*            pairs  = (int*)(ws + o_agg);
    int*            l1     = (int*)(ws + o_agg + (size_t)MAXNB * CAP * 4);

    hipMemsetAsync(gcur, 0, (size_t)(MAXNB + MAXL1) * 4, stream);  // gcur+gcur1

    int p1b = (E + 256 * C1 - 1) / (256 * C1);
    part1_k<<<p1b, 256, 0, stream>>>(src, dst, gcur1, l1, E, NL1);
    part2_k<<<NL1 * NCHK, 256, 0, stream>>>(l1, gcur1, gcur, pairs);
    scan_gcur_k<<<1, 1024, 0, stream>>>(gcur, bbase, NB, offsets, N);
    bucket_csr_k<<<NB, 256, 0, stream>>>(pairs, gcur, bbase, deg, offsets, srt, N, E);

    prep_w_k<<<(DIM * DIM + 255) / 256, 256, 0, stream>>>(W, wb);
    prescale_k<<<(N * (DIM / 4) + 255) / 256, 256, 0, stream>>>(feat, deg, feat8, N);
    aggregate_k<<<(int)(((size_t)N * 64 + 255) / 256), 256, 0, stream>>>(
        feat8, offsets, srt, agg, N, E);
    gemm_ep_k<<<(N + 127) / 128, 256, 0, stream>>>(agg, wb, deg, feat, init, out, N);
}